// Round 11
// baseline (208.450 us; speedup 1.0000x reference)
//
#include <hip/hip_runtime.h>
#include <hip/hip_fp16.h>

#define NLEVELS 8
#define NBANDS  64
#define CHUNK   1024   // samples per block in scatter (4 iters x 256 threads)

// RESOLUTIONS = [16, 29, 53, 98, 181, 332, 610, 1120]
__constant__ int   c_res[NLEVELS]   = {16, 29, 53, 98, 181, 332, 610, 1120};
__constant__ float c_scale[NLEVELS] = {7.5f, 14.0f, 26.0f, 48.5f, 90.0f, 165.5f, 304.5f, 559.5f};
// quad-index start of each level (quad index == texel index)
__constant__ int   c_qcum[NLEVELS]  = {0, 256, 1097, 3906, 13510, 46271, 156495, 528595};
#define QTOT8       1782995                 // quads, all 8 levels
#define QTAB_BYTES  ((size_t)QTOT8 * 32)

typedef float        f32x4 __attribute__((ext_vector_type(4)));
typedef unsigned int u32;
typedef u32          u32x4 __attribute__((ext_vector_type(4)));            // 16-B aligned
typedef u32          u32x8 __attribute__((ext_vector_type(8)));            // 32-B aligned

struct CbPtrs { const float* cb[NLEVELS]; };

__device__ __forceinline__ float2 up_h2(u32 v) {
    __half2 h = *reinterpret_cast<__half2*>(&v);
    return __half22float2(h);
}
__device__ __forceinline__ u32 pack_h2(float a, float b) {
    __half2 h = __floats2half2_rn(a, b);
    return *reinterpret_cast<u32*>(&h);
}
__device__ __forceinline__ int band_of(float cy) {
    float v = (cy + 1.0f) * 0.5f;
    int k = (int)(v * (float)NBANDS);
    return min(NBANDS - 1, max(0, k));
}

// ---------- fused prep: quad table (ALL 8 levels) + histogram ----------
#define PREP_TBLOCKS 2048
#define PREP_HBLOCKS 512
__global__ __launch_bounds__(256) void prep_kernel(CbPtrs p,
                                                   u32x4* __restrict__ qtab,
                                                   const float2* __restrict__ coords,
                                                   u32* __restrict__ gcount, int S) {
    if (blockIdx.x < PREP_TBLOCKS) {
        for (int t = blockIdx.x * 256 + threadIdx.x; t < QTOT8; t += PREP_TBLOCKS * 256) {
            int L = 0;
#pragma unroll
            for (int i = 1; i < NLEVELS; ++i) if (t >= c_qcum[i]) L = i;
            int i   = t - c_qcum[L];
            int res = c_res[L];
            int rr  = res * res;
            int y   = i / res, x = i - y * res;
            int xn  = min(x + 1, res - 1), yn = min(y + 1, res - 1);
            const float* cb = p.cb[L];
            int i00 = y * res + x,  i01 = y * res + xn;
            int i10 = yn * res + x, i11 = yn * res + xn;
            u32x4 w0, w1;
            w0.x = pack_h2(cb[i00], cb[i00 + rr]);
            w0.y = pack_h2(cb[i00 + 2 * rr], cb[i00 + 3 * rr]);
            w0.z = pack_h2(cb[i01], cb[i01 + rr]);
            w0.w = pack_h2(cb[i01 + 2 * rr], cb[i01 + 3 * rr]);
            w1.x = pack_h2(cb[i10], cb[i10 + rr]);
            w1.y = pack_h2(cb[i10 + 2 * rr], cb[i10 + 3 * rr]);
            w1.z = pack_h2(cb[i11], cb[i11 + rr]);
            w1.w = pack_h2(cb[i11 + 2 * rr], cb[i11 + 3 * rr]);
            qtab[2 * (size_t)t]     = w0;
            qtab[2 * (size_t)t + 1] = w1;
        }
    } else {
        __shared__ u32 h[NBANDS];
        for (int i = threadIdx.x; i < NBANDS; i += 256) h[i] = 0u;
        __syncthreads();
        int nb = gridDim.x - PREP_TBLOCKS;
        for (int s = (blockIdx.x - PREP_TBLOCKS) * 256 + threadIdx.x; s < S; s += nb * 256)
            atomicAdd(&h[band_of(coords[s].y)], 1u);
        __syncthreads();
        for (int i = threadIdx.x; i < NBANDS; i += 256)
            if (h[i]) atomicAdd(&gcount[i], h[i]);
    }
}

// ---------- scatter with inline band-start scan (gcursor2 pre-zeroed) ----------
__global__ __launch_bounds__(256) void scatter_kernel(const float2* __restrict__ coords,
                                                      const u32* __restrict__ gcount,
                                                      u32* __restrict__ gcursor2,
                                                      u32x4* __restrict__ recS, int S) {
    __shared__ u32 h[NBANDS];
    __shared__ u32 bandstart[NBANDS];
    __shared__ u32 rank_base[NBANDS];
    int s0 = blockIdx.x * CHUNK;
    for (int i = threadIdx.x; i < NBANDS; i += 256) h[i] = 0u;
    if (threadIdx.x == 0) {
        u32 acc = 0;
#pragma unroll
        for (int i = 0; i < NBANDS; ++i) { bandstart[i] = acc; acc += gcount[i]; }
    }
    __syncthreads();
    u32 myrank[CHUNK / 256];
    int myk[CHUNK / 256];
    float2 myc[CHUNK / 256];
#pragma unroll
    for (int it = 0; it < CHUNK / 256; ++it) {
        int s = s0 + it * 256 + threadIdx.x;
        if (s < S) {
            float2 c = coords[s];
            int k = band_of(c.y);
            myc[it] = c;
            myk[it] = k;
            myrank[it] = atomicAdd(&h[k], 1u);
        }
    }
    __syncthreads();
    for (int i = threadIdx.x; i < NBANDS; i += 256)
        rank_base[i] = bandstart[i] + (h[i] ? atomicAdd(&gcursor2[i], h[i]) : 0u);
    __syncthreads();
#pragma unroll
    for (int it = 0; it < CHUNK / 256; ++it) {
        int s = s0 + it * 256 + threadIdx.x;
        if (s < S) {
            u32 pos = rank_base[myk[it]] + myrank[it];
            u32x4 r;
            r.x = __float_as_uint(myc[it].x);
            r.y = __float_as_uint(myc[it].y);
            r.z = (u32)s;
            r.w = 0u;
            recS[pos] = r;
        }
    }
}

// ------- main: band-sorted, 8 threads x 2 samples (ILP-2), uniform quad gathers -------
__device__ __forceinline__ f32x4 sample_level(float cx, float cy, int L,
                                              const u32x4* __restrict__ qtab) {
    int   res   = c_res[L];
    float scale = c_scale[L];
    float px = (cx + 1.0f) * scale;
    float py = (cy + 1.0f) * scale;
    float xf = floorf(px), yf = floorf(py);
    float wx = px - xf,    wy = py - yf;
    int x0 = (int)xf, y0 = (int)yf;
    int xp = min(max(x0, 0), res - 2);  wx += (float)(x0 - xp);
    int yp = min(max(y0, 0), res - 2);  wy += (float)(y0 - yp);

    const u32x4* q = qtab + 2 * (size_t)(c_qcum[L] + yp * res + xp);
    u32x4 h0 = q[0];   // t00, t01
    u32x4 h1 = q[1];   // t10, t11

    float2 a00 = up_h2(h0.x), b00 = up_h2(h0.y);
    float2 a01 = up_h2(h0.z), b01 = up_h2(h0.w);
    float2 a10 = up_h2(h1.x), b10 = up_h2(h1.y);
    float2 a11 = up_h2(h1.z), b11 = up_h2(h1.w);

    float w00 = (1.0f - wx) * (1.0f - wy);
    float w01 = wx * (1.0f - wy);
    float w10 = (1.0f - wx) * wy;
    float w11 = wx * wy;

    f32x4 r;
    r.x = a00.x * w00 + a01.x * w01 + a10.x * w10 + a11.x * w11;
    r.y = a00.y * w00 + a01.y * w01 + a10.y * w10 + a11.y * w11;
    r.z = b00.x * w00 + b01.x * w01 + b10.x * w10 + b11.x * w11;
    r.w = b00.y * w00 + b01.y * w01 + b10.y * w10 + b11.y * w11;
    return r;
}

__global__ __launch_bounds__(256) void grid_sorted82(const u32x4* __restrict__ recS,
                                                     const u32x4* __restrict__ qtab,
                                                     f32x4* __restrict__ out, int S) {
    // XCD-contiguous swizzle (gridDim.x multiple of 8)
    int p  = blockIdx.x;
    int nb = gridDim.x;
    int b  = (p & 7) * (nb >> 3) + (p >> 3);
    int t  = b * 256 + threadIdx.x;
    int pr = t >> 3;
    int L  = t & 7;
    int sA = pr * 2;
    if (sA >= S) return;
    int sB = sA + 1;
    bool hasB = sB < S;

    u32x4 rA, rB;
    if (hasB) {
        u32x8 rr = *(const u32x8*)&recS[sA];   // adjacent records: one 32-B load
        rA.x = rr.s0; rA.y = rr.s1; rA.z = rr.s2; rA.w = rr.s3;
        rB.x = rr.s4; rB.y = rr.s5; rB.z = rr.s6; rB.w = rr.s7;
    } else {
        rA = recS[sA];
        rB = rA;
    }

    f32x4 oA = sample_level(__uint_as_float(rA.x), __uint_as_float(rA.y), L, qtab);
    f32x4 oB = sample_level(__uint_as_float(rB.x), __uint_as_float(rB.y), L, qtab);

    out[(size_t)(int)rA.z * 8 + L] = oA;
    if (hasB) out[(size_t)(int)rB.z * 8 + L] = oB;
}

// ---------------- generic fallback (levels != 8 or ws too small, raw fp32 cbs) ----------------
__global__ __launch_bounds__(256) void grid_generic(const float2* __restrict__ coords,
                                                    CbPtrs p, float4* __restrict__ out4,
                                                    int S, int levels) {
    int s = blockIdx.x * 256 + threadIdx.x;
    if (s >= S) return;
    float2 c = coords[s];
    for (int L = 0; L < levels; ++L) {
        int   res   = c_res[L];
        float scale = c_scale[L];
        float px = (c.x + 1.0f) * scale;
        float py = (c.y + 1.0f) * scale;
        float x0f = floorf(px), y0f = floorf(py);
        float wx = px - x0f,    wy = py - y0f;
        int rm1 = res - 1;
        int x0 = min(max((int)x0f, 0), rm1);
        int x1 = min(x0 + 1, rm1);
        int y0 = min(max((int)y0f, 0), rm1);
        int y1 = min(y0 + 1, rm1);
        int i00 = y0 * res + x0, i01 = y0 * res + x1, i10 = y1 * res + x0, i11 = y1 * res + x1;
        float w00 = (1.0f - wx) * (1.0f - wy);
        float w01 = wx * (1.0f - wy);
        float w10 = (1.0f - wx) * wy;
        float w11 = wx * wy;
        float4 r;
        const float* cb = p.cb[L];
        int rr = res * res;
        float* pr = &r.x;
#pragma unroll
        for (int f = 0; f < 4; ++f) {
            const float* cf = cb + f * rr;
            pr[f] = cf[i00] * w00 + cf[i01] * w01 + cf[i10] * w10 + cf[i11] * w11;
        }
        out4[(size_t)s * levels + L] = r;
    }
}

extern "C" void kernel_launch(void* const* d_in, const int* in_sizes, int n_in,
                              void* d_out, int out_size, void* d_ws, size_t ws_size,
                              hipStream_t stream) {
    const float2* coords = (const float2*)d_in[0];
    int S = in_sizes[0] / 2;                 // total samples B*N
    int levels = out_size / (S * 4);

    CbPtrs ptrs;
    for (int i = 0; i < NLEVELS; ++i) ptrs.cb[i] = (const float*)d_in[2 + i];

    // ws layout: qtab | gcount[64] gcursor2[64] | recS[S] (16 B each)
    size_t tab_bytes = (QTAB_BYTES + 255) & ~(size_t)255;
    size_t cnt_bytes = 512;
    size_t rec_bytes = (size_t)S * 16;
    size_t need = tab_bytes + cnt_bytes + rec_bytes;

    char*  ws       = (char*)d_ws;
    u32x4* qtab     = (u32x4*)ws;
    u32*   gcount   = (u32*)(ws + tab_bytes);
    u32*   gcursor2 = gcount + NBANDS;
    u32x4* recS     = (u32x4*)(ws + tab_bytes + cnt_bytes);

    if (levels != NLEVELS || ws_size < need) {
        int blocks = (S + 255) / 256;
        grid_generic<<<blocks, 256, 0, stream>>>(coords, ptrs, (float4*)d_out, S, levels);
        return;
    }

    hipMemsetAsync(gcount, 0, cnt_bytes, stream);
    prep_kernel<<<PREP_TBLOCKS + PREP_HBLOCKS, 256, 0, stream>>>(ptrs, qtab, coords, gcount, S);
    int nchunk = (S + CHUNK - 1) / CHUNK;
    scatter_kernel<<<nchunk, 256, 0, stream>>>(coords, gcount, gcursor2, recS, S);

    long long pairs = ((long long)S + 1) / 2;
    long long tot   = pairs * 8;
    int nb = (int)((tot + 255) / 256);
    nb = ((nb + 7) / 8) * 8;                 // multiple of 8 for bijective swizzle
    grid_sorted82<<<nb, 256, 0, stream>>>(recS, qtab, (f32x4*)d_out, S);
}

// Round 12
// 166.326 us; speedup vs baseline: 1.2533x; 1.2533x over previous
//
#include <hip/hip_runtime.h>
#include <hip/hip_fp16.h>

#define NLEVELS 8
#define NBANDS  64
#define CHUNK   1024   // samples per block in scatter (4 iters x 256 threads)

// RESOLUTIONS = [16, 29, 53, 98, 181, 332, 610, 1120]
__constant__ int   c_res[NLEVELS]   = {16, 29, 53, 98, 181, 332, 610, 1120};
__constant__ float c_scale[NLEVELS] = {7.5f, 14.0f, 26.0f, 48.5f, 90.0f, 165.5f, 304.5f, 559.5f};
__constant__ int   c_cum[NLEVELS]   = {0, 256, 1097, 3906, 13510, 46271, 156495, 528595};
#define TOTAL_TEXELS 1782995

typedef float        f32x4 __attribute__((ext_vector_type(4)));
typedef unsigned int u32;
typedef u32          u32x4  __attribute__((ext_vector_type(4)));           // 16-B aligned
typedef u32          u32x4a8 __attribute__((ext_vector_type(4), aligned(8)));

struct CbPtrs { const float* cb[NLEVELS]; };

__device__ __forceinline__ float2 up_h2(u32 v) {
    __half2 h = *reinterpret_cast<__half2*>(&v);
    return __half22float2(h);
}
__device__ __forceinline__ u32 pack_h2(float a, float b) {
    __half2 h = __floats2half2_rn(a, b);
    return *reinterpret_cast<u32*>(&h);
}
__device__ __forceinline__ int band_of(float cy) {
    float v = (cy + 1.0f) * 0.5f;
    int k = (int)(v * (float)NBANDS);
    return min(NBANDS - 1, max(0, k));
}

// ---------- fused prep: texel transpose (fp16 uint2) + y-band histogram ----------
#define PREP_TBLOCKS 1024
#define PREP_HBLOCKS 512
__global__ __launch_bounds__(256) void prep_kernel(CbPtrs p,
                                                   uint2* __restrict__ tcb,
                                                   const float2* __restrict__ coords,
                                                   u32* __restrict__ gcount, int S) {
    if (blockIdx.x < PREP_TBLOCKS) {
        for (int t = blockIdx.x * 256 + threadIdx.x; t < TOTAL_TEXELS; t += PREP_TBLOCKS * 256) {
            int L = 0;
#pragma unroll
            for (int i = 1; i < NLEVELS; ++i) if (t >= c_cum[i]) L = i;
            int i  = t - c_cum[L];
            int rr = c_res[L] * c_res[L];
            const float* cb = p.cb[L];
            uint2 tex;
            tex.x = pack_h2(cb[i],          cb[i + rr]);
            tex.y = pack_h2(cb[i + 2 * rr], cb[i + 3 * rr]);
            tcb[t] = tex;
        }
    } else {
        __shared__ u32 h[NBANDS];
        for (int i = threadIdx.x; i < NBANDS; i += 256) h[i] = 0u;
        __syncthreads();
        int nb = gridDim.x - PREP_TBLOCKS;
        for (int s = (blockIdx.x - PREP_TBLOCKS) * 256 + threadIdx.x; s < S; s += nb * 256)
            atomicAdd(&h[band_of(coords[s].y)], 1u);
        __syncthreads();
        for (int i = threadIdx.x; i < NBANDS; i += 256)
            if (h[i]) atomicAdd(&gcount[i], h[i]);
    }
}

// ---------- scatter with inline band-start scan (gcursor2 pre-zeroed) ----------
// record: {bits(cx), bits(cy), idx, 0} (16 B)
__global__ __launch_bounds__(256) void scatter_kernel(const float2* __restrict__ coords,
                                                      const u32* __restrict__ gcount,
                                                      u32* __restrict__ gcursor2,
                                                      u32x4* __restrict__ recS, int S) {
    __shared__ u32 h[NBANDS];
    __shared__ u32 bandstart[NBANDS];
    __shared__ u32 rank_base[NBANDS];
    int s0 = blockIdx.x * CHUNK;
    for (int i = threadIdx.x; i < NBANDS; i += 256) h[i] = 0u;
    if (threadIdx.x == 0) {
        u32 acc = 0;
#pragma unroll
        for (int i = 0; i < NBANDS; ++i) { bandstart[i] = acc; acc += gcount[i]; }
    }
    __syncthreads();
    u32 myrank[CHUNK / 256];
    int myk[CHUNK / 256];
    float2 myc[CHUNK / 256];
#pragma unroll
    for (int it = 0; it < CHUNK / 256; ++it) {
        int s = s0 + it * 256 + threadIdx.x;
        if (s < S) {
            float2 c = coords[s];
            int k = band_of(c.y);
            myc[it] = c;
            myk[it] = k;
            myrank[it] = atomicAdd(&h[k], 1u);
        }
    }
    __syncthreads();
    for (int i = threadIdx.x; i < NBANDS; i += 256)
        rank_base[i] = bandstart[i] + (h[i] ? atomicAdd(&gcursor2[i], h[i]) : 0u);
    __syncthreads();
#pragma unroll
    for (int it = 0; it < CHUNK / 256; ++it) {
        int s = s0 + it * 256 + threadIdx.x;
        if (s < S) {
            u32 pos = rank_base[myk[it]] + myrank[it];
            u32x4 r;
            r.x = __float_as_uint(myc[it].x);
            r.y = __float_as_uint(myc[it].y);
            r.z = (u32)s;
            r.w = 0u;
            recS[pos] = r;
        }
    }
}

// ------- main (R6 form): band-sorted, 8 threads per sample (one per level) -------
// Lanes 8k..8k+7 share sample s: one store instruction covers 8 samples x 128 B
// contiguous -> full-line coalesced writes. Gathers keep sorted L2 locality.
__global__ __launch_bounds__(256) void grid_sorted8(const u32x4* __restrict__ recS,
                                                    const uint2* __restrict__ tcb,
                                                    f32x4* __restrict__ out, int S) {
    // XCD-contiguous swizzle (gridDim.x multiple of 8)
    int p  = blockIdx.x;
    int nb = gridDim.x;
    int b  = (p & 7) * (nb >> 3) + (p >> 3);
    int t  = b * 256 + threadIdx.x;
    int s  = t >> 3;
    if (s >= S) return;
    int L  = t & 7;

    u32x4 rec = recS[s];                 // 8 lanes same 16-B record (broadcast)
    float cx = __uint_as_float(rec.x);
    float cy = __uint_as_float(rec.y);
    int  idx = (int)rec.z;

    int   res   = c_res[L];
    float scale = c_scale[L];
    const uint2* __restrict__ base = tcb + c_cum[L];

    float px = (cx + 1.0f) * scale;
    float py = (cy + 1.0f) * scale;
    float xf = floorf(px), yf = floorf(py);
    float wx = px - xf,    wy = py - yf;
    int x0 = (int)xf, y0 = (int)yf;
    int xp = min(max(x0, 0), res - 2);  wx += (float)(x0 - xp);
    int yp = min(max(y0, 0), res - 2);  wy += (float)(y0 - yp);
    const uint2* r0 = base + yp * res + xp;
    u32x4a8 t0 = *(const u32x4a8*)r0;          // texels (xp,yp),(xp+1,yp)
    u32x4a8 t1 = *(const u32x4a8*)(r0 + res);  // texels (xp,yp+1),(xp+1,yp+1)

    float2 a00 = up_h2(t0.x), b00 = up_h2(t0.y);
    float2 a01 = up_h2(t0.z), b01 = up_h2(t0.w);
    float2 a10 = up_h2(t1.x), b10 = up_h2(t1.y);
    float2 a11 = up_h2(t1.z), b11 = up_h2(t1.w);

    float w00 = (1.0f - wx) * (1.0f - wy);
    float w01 = wx * (1.0f - wy);
    float w10 = (1.0f - wx) * wy;
    float w11 = wx * wy;

    f32x4 r;
    r.x = a00.x * w00 + a01.x * w01 + a10.x * w10 + a11.x * w11;
    r.y = a00.y * w00 + a01.y * w01 + a10.y * w10 + a11.y * w11;
    r.z = b00.x * w00 + b01.x * w01 + b10.x * w10 + b11.x * w11;
    r.w = b00.y * w00 + b01.y * w01 + b10.y * w10 + b11.y * w11;

    out[(size_t)idx * 8 + L] = r;
}

// ---------------- generic fallback (levels != 8 or ws too small, raw fp32 cbs) ----------------
__global__ __launch_bounds__(256) void grid_generic(const float2* __restrict__ coords,
                                                    CbPtrs p, float4* __restrict__ out4,
                                                    int S, int levels) {
    int s = blockIdx.x * 256 + threadIdx.x;
    if (s >= S) return;
    float2 c = coords[s];
    for (int L = 0; L < levels; ++L) {
        int   res   = c_res[L];
        float scale = c_scale[L];
        float px = (c.x + 1.0f) * scale;
        float py = (c.y + 1.0f) * scale;
        float x0f = floorf(px), y0f = floorf(py);
        float wx = px - x0f,    wy = py - y0f;
        int rm1 = res - 1;
        int x0 = min(max((int)x0f, 0), rm1);
        int x1 = min(x0 + 1, rm1);
        int y0 = min(max((int)y0f, 0), rm1);
        int y1 = min(y0 + 1, rm1);
        int i00 = y0 * res + x0, i01 = y0 * res + x1, i10 = y1 * res + x0, i11 = y1 * res + x1;
        float w00 = (1.0f - wx) * (1.0f - wy);
        float w01 = wx * (1.0f - wy);
        float w10 = (1.0f - wx) * wy;
        float w11 = wx * wy;
        float4 r;
        const float* cb = p.cb[L];
        int rr = res * res;
        float* pr = &r.x;
#pragma unroll
        for (int f = 0; f < 4; ++f) {
            const float* cf = cb + f * rr;
            pr[f] = cf[i00] * w00 + cf[i01] * w01 + cf[i10] * w10 + cf[i11] * w11;
        }
        out4[(size_t)s * levels + L] = r;
    }
}

extern "C" void kernel_launch(void* const* d_in, const int* in_sizes, int n_in,
                              void* d_out, int out_size, void* d_ws, size_t ws_size,
                              hipStream_t stream) {
    const float2* coords = (const float2*)d_in[0];
    int S = in_sizes[0] / 2;                 // total samples B*N
    int levels = out_size / (S * 4);

    CbPtrs ptrs;
    for (int i = 0; i < NLEVELS; ++i) ptrs.cb[i] = (const float*)d_in[2 + i];

    // ws layout: tcb (uint2 texels) | gcount[64] gcursor2[64] | recS[S] (16 B each)
    size_t tcb_bytes = ((size_t)TOTAL_TEXELS * 8 + 255) & ~(size_t)255;
    size_t cnt_bytes = 512;
    size_t rec_bytes = (size_t)S * 16;
    size_t need = tcb_bytes + cnt_bytes + rec_bytes;

    char*  ws       = (char*)d_ws;
    uint2* tcb      = (uint2*)ws;
    u32*   gcount   = (u32*)(ws + tcb_bytes);
    u32*   gcursor2 = gcount + NBANDS;
    u32x4* recS     = (u32x4*)(ws + tcb_bytes + cnt_bytes);

    if (levels != NLEVELS || ws_size < need) {
        int blocks = (S + 255) / 256;
        grid_generic<<<blocks, 256, 0, stream>>>(coords, ptrs, (float4*)d_out, S, levels);
        return;
    }

    hipMemsetAsync(gcount, 0, cnt_bytes, stream);
    prep_kernel<<<PREP_TBLOCKS + PREP_HBLOCKS, 256, 0, stream>>>(ptrs, tcb, coords, gcount, S);
    int nchunk = (S + CHUNK - 1) / CHUNK;
    scatter_kernel<<<nchunk, 256, 0, stream>>>(coords, gcount, gcursor2, recS, S);

    long long total = (long long)S * 8;
    int nb = (int)((total + 255) / 256);
    nb = ((nb + 7) / 8) * 8;                 // multiple of 8 for bijective swizzle
    grid_sorted8<<<nb, 256, 0, stream>>>(recS, tcb, (f32x4*)d_out, S);
}